// Round 6
// baseline (441.637 us; speedup 1.0000x reference)
//
#include <hip/hip_runtime.h>
#include <hip/hip_bf16.h>
#include <stdint.h>

// CachedOPTAttention: B=4, T=1024, D=2048, H=32, HD=64, causal, idx=0.
// FP32 buffers; bf16-class error budget -> bf16 MFMA math inside.
//
// R8 = R7 resubmission (R7 bench died to container infra, no counters).
// R7: attention staging overhaul.
//   * V GEMM epilogue writes an extra pre-transposed bf16 copy vbT[b][h][d][t]
//     -> attention stages V with ONE global_load_lds per wave (pre-swizzled
//     source, zero-conflict XOR reads) instead of f32 load+convert+transpose.
//   * T14 async-stage split + double-buffered K/V in attention: issue next
//     tile's V gl2lds + K f32 loads BEFORE compute, K convert/ds_write after,
//     ONE barrier per tile (was two). HBM latency hides under MFMA+softmax.
//   * GEMMs keep the R6 structure (m97-class, BK=64, XOR swizzle, XCD swizzle,
//     zero bank conflicts, 824 TF) - at the structure ceiling, left alone.
//
// Memory plan (ws peak 32 MB - proven budget):
//   d_out: [0,16)  xb  (dead after V GEMM)   [16,32) qb (dead after attn)
//          [32,96) cache f32 (final output); O GEMM overwrites [0,32) last.
//   d_ws:  [0,16)  WTqk  -> (after QK GEMM)  vbT bf16
//          [16,24) WTv   -> (after V GEMM)   ctxb lower half
//          [16,32) ctxb  (written by attn)
//          [0,8)   WTo   (after attn, over dead vbT)

typedef __hip_bfloat16 bf16;
typedef unsigned short us;
typedef short s16x8 __attribute__((ext_vector_type(8)));
typedef float f32x4 __attribute__((ext_vector_type(4)));

#define T_SEQ   1024
#define D_MODEL 2048

__device__ inline us f2b(float f) {
    bf16 h = __float2bfloat16(f);
    return *(us*)&h;
}

typedef __attribute__((address_space(1))) const void gas_void;
typedef __attribute__((address_space(3))) void las_void;

__device__ inline void gl2lds16(const void* g, void* l) {
    // per-lane global src; LDS dest = wave-uniform base + lane*16
    __builtin_amdgcn_global_load_lds((gas_void*)g, (las_void*)l, 16, 0, 0);
}

// ---------------------------------------------------------------------------
// x[4096][2048] f32 -> bf16 (linear)
// ---------------------------------------------------------------------------
__global__ __launch_bounds__(256)
void cvtx_kernel(const float* __restrict__ x, us* __restrict__ xb)
{
    const size_t i = ((size_t)blockIdx.x * 256 + threadIdx.x) * 8;
    float4 a = *(const float4*)(x + i);
    float4 b = *(const float4*)(x + i + 4);
    union { uint4 u; us s[8]; } p;
    p.s[0] = f2b(a.x); p.s[1] = f2b(a.y); p.s[2] = f2b(a.z); p.s[3] = f2b(a.w);
    p.s[4] = f2b(b.x); p.s[5] = f2b(b.y); p.s[6] = f2b(b.z); p.s[7] = f2b(b.w);
    *(uint4*)(xb + i) = p.u;
}

// ---------------------------------------------------------------------------
// W[2048][2048] f32 (k-major) -> Wt + z*2048*2048: bf16 [N][K] (k contiguous).
// ---------------------------------------------------------------------------
__global__ __launch_bounds__(256)
void wtrans_kernel(const float* __restrict__ W0, const float* __restrict__ W1,
                   us* __restrict__ Wt)
{
    __shared__ float tile[64][65];
    const int z = blockIdx.z;
    const float* W = (z == 0) ? W0 : W1;
    us* dst = Wt + (size_t)z * D_MODEL * D_MODEL;

    const int tid = threadIdx.x;
    const int k0 = blockIdx.y * 64, n0 = blockIdx.x * 64;

    const int rr = tid >> 4, cc = (tid & 15) * 4;
    #pragma unroll
    for (int i = 0; i < 4; ++i) {
        float4 v = *(const float4*)(W + (size_t)(k0 + rr + i * 16) * D_MODEL + n0 + cc);
        tile[rr + i * 16][cc]     = v.x;
        tile[rr + i * 16][cc + 1] = v.y;
        tile[rr + i * 16][cc + 2] = v.z;
        tile[rr + i * 16][cc + 3] = v.w;
    }
    __syncthreads();

    const int nr = tid >> 3, kc = (tid & 7) * 8;
    #pragma unroll
    for (int i = 0; i < 2; ++i) {
        const int n = nr + i * 32;
        union { uint4 u; us s[8]; } p;
        #pragma unroll
        for (int j = 0; j < 8; ++j) p.s[j] = f2b(tile[kc + j][n]);
        *(uint4*)(dst + (size_t)(n0 + n) * D_MODEL + k0 + kc) = p.u;
    }
}

// ---------------------------------------------------------------------------
// GEMM (m97 structure, BK=64, R6-proven): C[4096, N] = A(bf16) @ Bt^T + bias.
// XOR-swizzled LDS (zero bank conflicts), XCD block swizzle.
// MODE 0: f32 out (out0), bias b0.                          (O GEMM)
// MODE 4: seg by n0>>11: 0 -> bf16 qb scaled 1/8 (bias b0),
//         1 -> f32 cache slot 0 (bias b1).                  (QK GEMM, N=4096)
// MODE 5: f32 cache slot 1 (bias b0) + bf16 vbT[b][h][d][t] (V GEMM, N=2048)
// ---------------------------------------------------------------------------
template<int MODE>
__global__ __launch_bounds__(256, 3)
void gemm128_kernel(const us* __restrict__ A, const us* __restrict__ Bt,
                    const float* __restrict__ b0, const float* __restrict__ b1,
                    float* __restrict__ out0, float* __restrict__ out1,
                    us* __restrict__ vbt, const int* __restrict__ idxp)
{
    __shared__ __align__(16) us As[128 * 64];   // 16 KB
    __shared__ __align__(16) us Bs[128 * 64];   // 16 KB

    const int tid  = threadIdx.x;
    const int wv   = tid >> 6;       // 0..3
    const int lane = tid & 63;
    const int quad = lane >> 4;
    const int l15  = lane & 15;
    const int wm   = wv >> 1;        // 0..1
    const int wn   = wv & 1;         // 0..1

    // bijective XCD swizzle (both grids: nwg % 8 == 0)
    const int gx  = gridDim.x;
    const int nwg = gx * gridDim.y;
    int bid = blockIdx.y * gx + blockIdx.x;
    bid = (bid & 7) * (nwg >> 3) + (bid >> 3);
    const int m0 = (bid / gx) * 128;
    const int n0 = (bid % gx) * 128;

    // staging: 8 rows per gl2lds call; lane l -> row (l>>3), chunk (l&7)^(l>>3)
    const int srow = lane >> 3;
    const int scol = ((lane & 7) ^ srow) * 8;
    const us* aG = A  + (size_t)(m0 + wv * 32 + srow) * D_MODEL + scol;
    const us* bG = Bt + (size_t)(n0 + wv * 32 + srow) * D_MODEL + scol;
    us* aL = As + wv * 32 * 64;
    us* bL = Bs + wv * 32 * 64;

    f32x4 acc[4][4];
    #pragma unroll
    for (int mi = 0; mi < 4; ++mi)
        #pragma unroll
        for (int ni = 0; ni < 4; ++ni) acc[mi][ni] = f32x4{0.f, 0.f, 0.f, 0.f};

    const int xr = l15 & 7;
    #define LDA(MI, KK) (*(const s16x8*)(As + (wm * 64 + (MI) * 16 + l15) * 64 \
                          + ((((KK) * 4 + quad) ^ xr) * 8)))
    #define LDB(NI, KK) (*(const s16x8*)(Bs + (wn * 64 + (NI) * 16 + l15) * 64 \
                          + ((((KK) * 4 + quad) ^ xr) * 8)))

    for (int k0 = 0; k0 < D_MODEL; k0 += 64) {
        #pragma unroll
        for (int g = 0; g < 4; ++g) {
            gl2lds16(aG + k0 + g * 8 * D_MODEL, aL + g * 512);
            gl2lds16(bG + k0 + g * 8 * D_MODEL, bL + g * 512);
        }
        __syncthreads();

        #pragma unroll
        for (int kk = 0; kk < 2; ++kk) {
            s16x8 af[4], bfr[4];
            #pragma unroll
            for (int mi = 0; mi < 4; ++mi) af[mi] = LDA(mi, kk);
            #pragma unroll
            for (int ni = 0; ni < 4; ++ni) bfr[ni] = LDB(ni, kk);
            #pragma unroll
            for (int mi = 0; mi < 4; ++mi)
                #pragma unroll
                for (int ni = 0; ni < 4; ++ni)
                    acc[mi][ni] = __builtin_amdgcn_mfma_f32_16x16x32_bf16(
                        af[mi], bfr[ni], acc[mi][ni], 0, 0, 0);
        }
        __syncthreads();
    }
    #undef LDA
    #undef LDB

    const int seg = (MODE == 4) ? (n0 >> 11) : 0;
    const float* bias = (MODE == 4) ? (seg == 0 ? b0 : b1) : b0;
    const int idx = (MODE == 0) ? 0 : idxp[0];

    #pragma unroll
    for (int ni = 0; ni < 4; ++ni) {
        const int col = n0 + wn * 64 + ni * 16 + l15;
        const int cl  = col & (D_MODEL - 1);
        const float bv = bias[cl];
        #pragma unroll
        for (int mi = 0; mi < 4; ++mi) {
            float vv[4];
            #pragma unroll
            for (int r = 0; r < 4; ++r) {
                const int m = m0 + wm * 64 + mi * 16 + quad * 4 + r;
                const float v = acc[mi][ni][r] + bv;
                if (MODE == 0) {
                    out0[(size_t)m * D_MODEL + cl] = v;
                } else if (MODE == 4) {
                    if (seg == 0) {
                        ((us*)out0)[(size_t)m * D_MODEL + cl] = f2b(v * 0.125f);
                    } else {
                        const int b  = m >> 10;
                        const int tt = ((m & 1023) + idx) & 1023;
                        out1[((size_t)(b * 2 + 0) * T_SEQ + tt) * D_MODEL + cl] = v;
                    }
                } else {  // MODE 5
                    const int b  = m >> 10;
                    const int tt = ((m & 1023) + idx) & 1023;
                    out1[((size_t)(b * 2 + 1) * T_SEQ + tt) * D_MODEL + cl] = v;
                    vv[r] = v;
                }
            }
            if (MODE == 5) {
                const int tok0 = m0 + wm * 64 + mi * 16 + quad * 4;
                const int bb = tok0 >> 10, t0 = tok0 & 1023;
                const int hh = cl >> 6, dd = cl & 63;
                ushort4 pv;
                pv.x = f2b(vv[0]); pv.y = f2b(vv[1]);
                pv.z = f2b(vv[2]); pv.w = f2b(vv[3]);
                *(ushort4*)(vbt + (size_t)((bb * 32 + hh) * 64 + dd) * 1024 + t0) = pv;
            }
        }
    }
}

// ---------------------------------------------------------------------------
// MFMA flash attention, QBLK=128, double-buffered K/V, T14 async staging.
// Per tile: issue next-V gl2lds (from pre-transposed bf16 vbT, pre-swizzled
// source) + next-K f32 global loads -> compute (QK MFMA, online softmax,
// P via Qs-reuse, PV MFMA with XOR-swizzled V reads) -> K convert+ds_write
// -> ONE barrier. Fully-masked waves skip compute.
// ---------------------------------------------------------------------------
#define LDW 72

__global__ __launch_bounds__(512, 4)
void attn_mfma_kernel(const us* __restrict__ q, const float* __restrict__ cache,
                      const us* __restrict__ vbt, us* __restrict__ ctx)
{
    __shared__ __align__(16) us Qs[128 * LDW];   // 18.4 KB; reused as Ps
    __shared__ __align__(16) us Ks[2][64 * LDW]; // 18.4 KB
    __shared__ __align__(16) us Vt[2][64 * 64];  // 16 KB   (total 52.8 KB)

    const int tid  = threadIdx.x;
    const int wave = tid >> 6;          // 0..7
    const int lane = tid & 63;
    const int quad = lane >> 4;
    const int l15  = lane & 15;
    const int xr   = l15 & 7;

    const int bh = blockIdx.x;          // b*32 + h
    const int b  = bh >> 5;
    const int h  = bh & 31;
    const int qt = 7 - blockIdx.y;      // query tile 0..7 (128 rows each)

    const float* kbase = cache + ((size_t)(b * 2 + 0) * T_SEQ) * D_MODEL + h * 64;
    const us* vb_bh = vbt + (size_t)((b * 32 + h) * 64) * 1024;   // [64 d][1024 t]

    // ---- stage Q tile (128q x 64d), bf16 copy ----
    {
        const int qrow = tid >> 2;
        const int qp   = tid & 3;
        const uint4* qg = (const uint4*)(q + (size_t)(b * T_SEQ + qt * 128 + qrow) * D_MODEL
                                           + h * 64 + qp * 16);
        uint4 q0 = qg[0], q1 = qg[1];
        *(uint4*)(Qs + qrow * LDW + qp * 16)     = q0;
        *(uint4*)(Qs + qrow * LDW + qp * 16 + 8) = q1;
    }

    // ---- staging coords ----
    const int ksrow = tid >> 3;                 // 0..63 (K row)
    const int kp8   = tid & 7;                  // 8-d chunk
    const int vrow  = lane >> 3;                // 0..7 (d row within wave's 8)
    const int vchk  = (lane & 7) ^ vrow;        // pre-swizzled key-chunk
    const us* vG = vb_bh + (size_t)(wave * 8 + vrow) * 1024 + vchk * 8;

    const int nkt = 2 * qt + 2;

    // ---- prologue: stage tile 0 into buf 0 ----
    gl2lds16(vG, (us*)Vt[0] + wave * 512);
    {
        const float4* kg = (const float4*)(kbase + (size_t)ksrow * D_MODEL + kp8 * 8);
        float4 k0 = kg[0], k1 = kg[1];
        union { uint4 u; us s[8]; } p;
        p.s[0] = f2b(k0.x); p.s[1] = f2b(k0.y); p.s[2] = f2b(k0.z); p.s[3] = f2b(k0.w);
        p.s[4] = f2b(k1.x); p.s[5] = f2b(k1.y); p.s[6] = f2b(k1.z); p.s[7] = f2b(k1.w);
        *(uint4*)(&Ks[0][ksrow * LDW + kp8 * 8]) = p.u;
    }
    __syncthreads();   // Q + tile-0 staging visible

    // hoist Q A-frags; Qs LDS becomes Ps
    const s16x8 qf0 = *(const s16x8*)(Qs + (wave * 16 + l15) * LDW + quad * 8);
    const s16x8 qf1 = *(const s16x8*)(Qs + (wave * 16 + l15) * LDW + 32 + quad * 8);

    f32x4 oacc[4];
    #pragma unroll
    for (int t = 0; t < 4; ++t) oacc[t] = f32x4{0.f, 0.f, 0.f, 0.f};
    float m_run[4] = {-1e30f, -1e30f, -1e30f, -1e30f};
    float l_run[4] = {0.f, 0.f, 0.f, 0.f};

    for (int kt = 0; kt < nkt; ++kt) {
        const int buf = kt & 1;
        const bool more = (kt + 1 < nkt);

        // ---- T14 issue-early: next tile's V (gl2lds) + K (f32 -> regs) ----
        float4 nk0, nk1;
        if (more) {
            gl2lds16(vG + (kt + 1) * 64, (us*)Vt[buf ^ 1] + wave * 512);
            const float4* kg = (const float4*)(kbase
                + (size_t)((kt + 1) * 64 + ksrow) * D_MODEL + kp8 * 8);
            nk0 = kg[0]; nk1 = kg[1];
        }

        const int kbr = kt * 64 - qt * 128;
        if (kbr < wave * 16 + 16) {          // else fully masked for this wave
            const us* kb_ = Ks[buf];
            const us* vb_ = (const us*)Vt[buf];

            // ---- S = Q @ K^T ----
            f32x4 sacc[4];
            #pragma unroll
            for (int t = 0; t < 4; ++t) sacc[t] = f32x4{0.f, 0.f, 0.f, 0.f};
            #pragma unroll
            for (int t = 0; t < 4; ++t) {
                s16x8 kf0 = *(const s16x8*)(kb_ + (t * 16 + l15) * LDW + quad * 8);
                s16x8 kf1 = *(const s16x8*)(kb_ + (t * 16 + l15) * LDW + 32 + quad * 8);
                sacc[t] = __builtin_amdgcn_mfma_f32_16x16x32_bf16(qf0, kf0, sacc[t], 0, 0, 0);
                sacc[t] = __builtin_amdgcn_mfma_f32_16x16x32_bf16(qf1, kf1, sacc[t], 0, 0, 0);
            }

            if (kbr + 63 > wave * 16) {      // diagonal-straddling: apply mask
                #pragma unroll
                for (int t = 0; t < 4; ++t) {
                    const int keyl = kbr + t * 16 + l15;
                    #pragma unroll
                    for (int r = 0; r < 4; ++r) {
                        if (keyl > wave * 16 + quad * 4 + r) sacc[t][r] = -1e30f;
                    }
                }
            }

            // ---- online softmax (rows live in lane quads) ----
            float rmax[4];
            #pragma unroll
            for (int r = 0; r < 4; ++r)
                rmax[r] = fmaxf(fmaxf(sacc[0][r], sacc[1][r]), fmaxf(sacc[2][r], sacc[3][r]));
            #pragma unroll
            for (int off = 1; off < 16; off <<= 1) {
                #pragma unroll
                for (int r = 0; r < 4; ++r) rmax[r] = fmaxf(rmax[r], __shfl_xor(rmax[r], off, 16));
            }
            float alpha[4];
            #pragma unroll
            for (int r = 0; r < 4; ++r) {
                const float mnew = fmaxf(m_run[r], rmax[r]);
                alpha[r] = __expf(m_run[r] - mnew);
                m_run[r] = mnew;
            }
            float rsum[4] = {0.f, 0.f, 0.f, 0.f};
            #pragma unroll
            for (int t = 0; t < 4; ++t) {
                #pragma unroll
                for (int r = 0; r < 4; ++r) {
                    const float p = __expf(sacc[t][r] - m_run[r]);
                    sacc[t][r] = p;
                    rsum[r] += p;
                }
            }
            #pragma unroll
            for (int off = 1; off < 16; off <<= 1) {
                #pragma unroll
                for (int r = 0; r < 4; ++r) rsum[r] += __shfl_xor(rsum[r], off, 16);
            }
            #pragma unroll
            for (int r = 0; r < 4; ++r) l_run[r] = l_run[r] * alpha[r] + rsum[r];
            #pragma unroll
            for (int t = 0; t < 4; ++t) {
                #pragma unroll
                for (int r = 0; r < 4; ++r) oacc[t][r] *= alpha[r];
            }

            // ---- P -> LDS (per-wave private 16-row slab of reused Qs) ----
            #pragma unroll
            for (int t = 0; t < 4; ++t) {
                #pragma unroll
                for (int r = 0; r < 4; ++r)
                    Qs[(wave * 16 + quad * 4 + r) * LDW + t * 16 + l15] = f2b(sacc[t][r]);
            }
            // same-wave write->read ordered by lgkmcnt

            // ---- O += P @ V^T (V in linear [d][key] LDS, XOR-swizzled) ----
            s16x8 pf0 = *(const s16x8*)(Qs + (wave * 16 + l15) * LDW + quad * 8);
            s16x8 pf1 = *(const s16x8*)(Qs + (wave * 16 + l15) * LDW + 32 + quad * 8);
            #pragma unroll
            for (int t = 0; t < 4; ++t) {
                s16x8 vf0 = *(const s16x8*)(vb_ + (t * 16 + l15) * 64 + ((quad ^ xr) * 8));
                s16x8 vf1 = *(const s16x8*)(vb_ + (t * 16 + l15) * 64 + (((4 + quad) ^ xr) * 8));
                oacc[t] = __builtin_amdgcn_mfma_f32_16x16x32_bf16(pf0, vf0, oacc[t], 0, 0, 0);
                oacc[t] = __builtin_amdgcn_mfma_f32_16x16x32_bf16(pf1, vf1, oacc[t], 0, 0, 0);
            }
        }

        // ---- T14 write-late: K convert + ds_write into buf^1 ----
        if (more) {
            union { uint4 u; us s[8]; } p;
            p.s[0] = f2b(nk0.x); p.s[1] = f2b(nk0.y); p.s[2] = f2b(nk0.z); p.s[3] = f2b(nk0.w);
            p.s[4] = f2b(nk1.x); p.s[5] = f2b(nk1.y); p.s[6] = f2b(nk1.z); p.s[7] = f2b(nk1.w);
            *(uint4*)(&Ks[buf ^ 1][ksrow * LDW + kp8 * 8]) = p.u;
        }
        __syncthreads();   // drains gl2lds (vmcnt) + ds_write (lgkm); flips buffers
    }

    // ---- epilogue: ctx (bf16) = O / l ----
    float invl[4];
    #pragma unroll
    for (int r = 0; r < 4; ++r) invl[r] = 1.0f / l_run[r];
    #pragma unroll
    for (int r = 0; r < 4; ++r) {
        const int qrow = qt * 128 + wave * 16 + quad * 4 + r;
        us* orow = ctx + (size_t)(b * T_SEQ + qrow) * D_MODEL + h * 64;
        #pragma unroll
        for (int t = 0; t < 4; ++t) orow[t * 16 + l15] = f2b(oacc[t][r] * invl[r]);
    }
}

// ---------------------------------------------------------------------------
extern "C" void kernel_launch(void* const* d_in, const int* in_sizes, int n_in,
                              void* d_out, int out_size, void* d_ws, size_t ws_size,
                              hipStream_t stream)
{
    const float* x    = (const float*)d_in[0];
    const int*   idxp = (const int*)d_in[3];
    const float* Wq   = (const float*)d_in[4];
    const float* bq   = (const float*)d_in[5];
    const float* Wk   = (const float*)d_in[6];
    const float* bk   = (const float*)d_in[7];
    const float* Wv   = (const float*)d_in[8];
    const float* bv   = (const float*)d_in[9];
    const float* Wo   = (const float*)d_in[10];
    const float* bo   = (const float*)d_in[11];

    float* out      = (float*)d_out;
    us*    xb       = (us*)d_out;                                   // [0,16MB)
    us*    qb       = (us*)d_out + (size_t)8 * 1024 * 1024;         // [16,32MB)
    float* cacheOut = out + (size_t)4 * T_SEQ * D_MODEL;            // [32,96MB)

    us* WTqk = (us*)d_ws;                                           // [0,16MB)
    us* WTv  = (us*)d_ws + (size_t)8 * 1024 * 1024;                 // [16,24MB)
    us* vbt  = (us*)d_ws;                                           // [0,16MB)  after QK
    us* ctxb = (us*)d_ws + (size_t)8 * 1024 * 1024;                 // [16,32MB) after V
    us* WTo  = (us*)d_ws;                                           // [0,8MB)   after attn

    const dim3 tb(256);

    cvtx_kernel<<<dim3(4096), tb, 0, stream>>>(x, xb);
    wtrans_kernel<<<dim3(32, 32, 2), tb, 0, stream>>>(Wq, Wk, WTqk);

    // fused QK: N = 4096 -> 32 x 32 = 1024 blocks
    gemm128_kernel<4><<<dim3(32, 32), tb, 0, stream>>>(
        xb, WTqk, bq, bk, (float*)qb, cacheOut, nullptr, idxp);

    wtrans_kernel<<<dim3(32, 32, 1), tb, 0, stream>>>(Wv, Wv, WTv);

    // V: N = 2048 -> 16 x 32 = 512 blocks; writes cache slot 1 + vbT
    gemm128_kernel<5><<<dim3(16, 32), tb, 0, stream>>>(
        xb, WTv, bv, nullptr, nullptr, cacheOut, vbt, idxp);

    attn_mfma_kernel<<<dim3(128, 8), dim3(512), 0, stream>>>(qb, cacheOut, vbt, ctxb);

    wtrans_kernel<<<dim3(32, 32, 1), tb, 0, stream>>>(Wo, Wo, WTo);

    // O GEMM: N = 2048 -> 16 x 32 = 512 blocks
    gemm128_kernel<0><<<dim3(16, 32), tb, 0, stream>>>(
        ctxb, WTo, bo, nullptr, out, nullptr, nullptr, nullptr);
}

// Round 7
// 437.620 us; speedup vs baseline: 1.0092x; 1.0092x over previous
//
#include <hip/hip_runtime.h>
#include <hip/hip_bf16.h>
#include <stdint.h>

// CachedOPTAttention: B=4, T=1024, D=2048, H=32, HD=64, causal, idx=0.
// FP32 buffers; bf16-class error budget -> bf16 MFMA math inside.
//
// R9: re-fuse QKV (R6's 824 TF MODE-3 GEMM, N=6144) and generate the
// pre-transposed bf16 V copy via a dedicated LDS-tiled transpose kernel
// (v2t: cache slot1 f32 -> vbT bf16, coalesced both sides) instead of the
// R8 V-GEMM epilogue scatter (2KB-stride ushort4 writes, ~64 transactions
// per store). Attention unchanged from R8 (T14 async staging, 1 barrier).
//
// Workspace timeline (peak 32 MB, proven):
//   d_out: [0,16) xb (dead after QKV) | [16,32) qb (dead after attn)
//          [32,96) cache f32 (final);  O GEMM overwrites [0,32) last.
//   d_ws:  [0,24) WT3 --after QKV--> [0,16) vbT, [16,32) ctxb
//          --after attn--> [0,8) WTo (over dead vbT)

typedef __hip_bfloat16 bf16;
typedef unsigned short us;
typedef short s16x8 __attribute__((ext_vector_type(8)));
typedef float f32x4 __attribute__((ext_vector_type(4)));

#define T_SEQ   1024
#define D_MODEL 2048

__device__ inline us f2b(float f) {
    bf16 h = __float2bfloat16(f);
    return *(us*)&h;
}

typedef __attribute__((address_space(1))) const void gas_void;
typedef __attribute__((address_space(3))) void las_void;

__device__ inline void gl2lds16(const void* g, void* l) {
    // per-lane global src; LDS dest = wave-uniform base + lane*16
    __builtin_amdgcn_global_load_lds((gas_void*)g, (las_void*)l, 16, 0, 0);
}

// ---------------------------------------------------------------------------
// x[4096][2048] f32 -> bf16 (linear)
// ---------------------------------------------------------------------------
__global__ __launch_bounds__(256)
void cvtx_kernel(const float* __restrict__ x, us* __restrict__ xb)
{
    const size_t i = ((size_t)blockIdx.x * 256 + threadIdx.x) * 8;
    float4 a = *(const float4*)(x + i);
    float4 b = *(const float4*)(x + i + 4);
    union { uint4 u; us s[8]; } p;
    p.s[0] = f2b(a.x); p.s[1] = f2b(a.y); p.s[2] = f2b(a.z); p.s[3] = f2b(a.w);
    p.s[4] = f2b(b.x); p.s[5] = f2b(b.y); p.s[6] = f2b(b.z); p.s[7] = f2b(b.w);
    *(uint4*)(xb + i) = p.u;
}

// ---------------------------------------------------------------------------
// W[2048][2048] f32 (k-major) -> Wt + z*2048*2048: bf16 [N][K] (k contiguous).
// ---------------------------------------------------------------------------
__global__ __launch_bounds__(256)
void wtrans_kernel(const float* __restrict__ W0, const float* __restrict__ W1,
                   const float* __restrict__ W2, us* __restrict__ Wt)
{
    __shared__ float tile[64][65];
    const int z = blockIdx.z;
    const float* W = (z == 0) ? W0 : (z == 1) ? W1 : W2;
    us* dst = Wt + (size_t)z * D_MODEL * D_MODEL;

    const int tid = threadIdx.x;
    const int k0 = blockIdx.y * 64, n0 = blockIdx.x * 64;

    const int rr = tid >> 4, cc = (tid & 15) * 4;
    #pragma unroll
    for (int i = 0; i < 4; ++i) {
        float4 v = *(const float4*)(W + (size_t)(k0 + rr + i * 16) * D_MODEL + n0 + cc);
        tile[rr + i * 16][cc]     = v.x;
        tile[rr + i * 16][cc + 1] = v.y;
        tile[rr + i * 16][cc + 2] = v.z;
        tile[rr + i * 16][cc + 3] = v.w;
    }
    __syncthreads();

    const int nr = tid >> 3, kc = (tid & 7) * 8;
    #pragma unroll
    for (int i = 0; i < 2; ++i) {
        const int n = nr + i * 32;
        union { uint4 u; us s[8]; } p;
        #pragma unroll
        for (int j = 0; j < 8; ++j) p.s[j] = f2b(tile[kc + j][n]);
        *(uint4*)(dst + (size_t)(n0 + n) * D_MODEL + k0 + kc) = p.u;
    }
}

// ---------------------------------------------------------------------------
// v2t: cache slot1 f32 [b][t][h*64+d] -> vbT bf16 [b][h][d][t].
// 64t x 64d LDS tile per block; coalesced f32 reads, coalesced bf16 writes.
// Grid (16 t-tiles, 32 h, 4 b), 256 threads.
// ---------------------------------------------------------------------------
__global__ __launch_bounds__(256)
void v2t_kernel(const float* __restrict__ cache, us* __restrict__ vbt)
{
    __shared__ float tile[64][65];
    const int t0 = blockIdx.x * 64;
    const int h  = blockIdx.y;
    const int b  = blockIdx.z;

    const float* src = cache + ((size_t)(b * 2 + 1) * T_SEQ) * D_MODEL + h * 64;

    const int tid = threadIdx.x;
    const int rr = tid >> 4, cc = (tid & 15) * 4;
    #pragma unroll
    for (int i = 0; i < 4; ++i) {
        float4 v = *(const float4*)(src + (size_t)(t0 + rr + i * 16) * D_MODEL + cc);
        tile[rr + i * 16][cc]     = v.x;
        tile[rr + i * 16][cc + 1] = v.y;
        tile[rr + i * 16][cc + 2] = v.z;
        tile[rr + i * 16][cc + 3] = v.w;
    }
    __syncthreads();

    const int dr = tid >> 3, tc = (tid & 7) * 8;
    #pragma unroll
    for (int i = 0; i < 2; ++i) {
        const int d = dr + i * 32;
        union { uint4 u; us s[8]; } p;
        #pragma unroll
        for (int j = 0; j < 8; ++j) p.s[j] = f2b(tile[tc + j][d]);
        *(uint4*)(vbt + (size_t)((b * 32 + h) * 64 + d) * 1024 + t0 + tc) = p.u;
    }
}

// ---------------------------------------------------------------------------
// GEMM (m97 structure, BK=64, R6-proven): C[4096, N] = A(bf16) @ Bt^T + bias.
// XOR-swizzled LDS (zero bank conflicts), bijective XCD block swizzle.
// MODE 0: f32 out (out0), bias b0.                       (O GEMM)
// MODE 3: col routing by n0>>11: 0 -> bf16 qb scaled 1/8 (bias b0),
//         1/2 -> f32 cache slot 0/1 (bias b1/b2).        (QKV GEMM, N=6144)
// ---------------------------------------------------------------------------
template<int MODE>
__global__ __launch_bounds__(256, 3)
void gemm128_kernel(const us* __restrict__ A, const us* __restrict__ Bt,
                    const float* __restrict__ b0, const float* __restrict__ b1,
                    const float* __restrict__ b2,
                    float* __restrict__ out0, float* __restrict__ out1,
                    const int* __restrict__ idxp)
{
    __shared__ __align__(16) us As[128 * 64];   // 16 KB
    __shared__ __align__(16) us Bs[128 * 64];   // 16 KB

    const int tid  = threadIdx.x;
    const int wv   = tid >> 6;       // 0..3
    const int lane = tid & 63;
    const int quad = lane >> 4;
    const int l15  = lane & 15;
    const int wm   = wv >> 1;        // 0..1
    const int wn   = wv & 1;         // 0..1

    // bijective XCD swizzle (grids 1536 / 512: nwg % 8 == 0)
    const int gx  = gridDim.x;
    const int nwg = gx * gridDim.y;
    int bid = blockIdx.y * gx + blockIdx.x;
    bid = (bid & 7) * (nwg >> 3) + (bid >> 3);
    const int m0 = (bid / gx) * 128;
    const int n0 = (bid % gx) * 128;

    // staging: 8 rows per gl2lds call; lane l -> row (l>>3), chunk (l&7)^(l>>3)
    const int srow = lane >> 3;
    const int scol = ((lane & 7) ^ srow) * 8;
    const us* aG = A  + (size_t)(m0 + wv * 32 + srow) * D_MODEL + scol;
    const us* bG = Bt + (size_t)(n0 + wv * 32 + srow) * D_MODEL + scol;
    us* aL = As + wv * 32 * 64;
    us* bL = Bs + wv * 32 * 64;

    f32x4 acc[4][4];
    #pragma unroll
    for (int mi = 0; mi < 4; ++mi)
        #pragma unroll
        for (int ni = 0; ni < 4; ++ni) acc[mi][ni] = f32x4{0.f, 0.f, 0.f, 0.f};

    const int xr = l15 & 7;
    #define LDA(MI, KK) (*(const s16x8*)(As + (wm * 64 + (MI) * 16 + l15) * 64 \
                          + ((((KK) * 4 + quad) ^ xr) * 8)))
    #define LDB(NI, KK) (*(const s16x8*)(Bs + (wn * 64 + (NI) * 16 + l15) * 64 \
                          + ((((KK) * 4 + quad) ^ xr) * 8)))

    for (int k0 = 0; k0 < D_MODEL; k0 += 64) {
        #pragma unroll
        for (int g = 0; g < 4; ++g) {
            gl2lds16(aG + k0 + g * 8 * D_MODEL, aL + g * 512);
            gl2lds16(bG + k0 + g * 8 * D_MODEL, bL + g * 512);
        }
        __syncthreads();

        #pragma unroll
        for (int kk = 0; kk < 2; ++kk) {
            s16x8 af[4], bfr[4];
            #pragma unroll
            for (int mi = 0; mi < 4; ++mi) af[mi] = LDA(mi, kk);
            #pragma unroll
            for (int ni = 0; ni < 4; ++ni) bfr[ni] = LDB(ni, kk);
            #pragma unroll
            for (int mi = 0; mi < 4; ++mi)
                #pragma unroll
                for (int ni = 0; ni < 4; ++ni)
                    acc[mi][ni] = __builtin_amdgcn_mfma_f32_16x16x32_bf16(
                        af[mi], bfr[ni], acc[mi][ni], 0, 0, 0);
        }
        __syncthreads();
    }
    #undef LDA
    #undef LDB

    const int seg = (MODE == 3) ? (n0 >> 11) : 0;
    const float* bias = (MODE == 3) ? (seg == 0 ? b0 : (seg == 1 ? b1 : b2)) : b0;
    const int idx = (MODE == 3 && seg > 0) ? idxp[0] : 0;

    #pragma unroll
    for (int ni = 0; ni < 4; ++ni) {
        const int col = n0 + wn * 64 + ni * 16 + l15;
        const int cl  = col & (D_MODEL - 1);
        const float bv = bias[cl];
        #pragma unroll
        for (int mi = 0; mi < 4; ++mi) {
            #pragma unroll
            for (int r = 0; r < 4; ++r) {
                const int m = m0 + wm * 64 + mi * 16 + quad * 4 + r;
                const float v = acc[mi][ni][r] + bv;
                if (MODE == 0) {
                    out0[(size_t)m * D_MODEL + cl] = v;
                } else {
                    if (seg == 0) {
                        ((us*)out0)[(size_t)m * D_MODEL + cl] = f2b(v * 0.125f);
                    } else {
                        const int b  = m >> 10;
                        const int tt = ((m & 1023) + idx) & 1023;
                        out1[((size_t)(b * 2 + (seg - 1)) * T_SEQ + tt) * D_MODEL + cl] = v;
                    }
                }
            }
        }
    }
}

// ---------------------------------------------------------------------------
// MFMA flash attention, QBLK=128, double-buffered K/V, T14 async staging
// (unchanged from R8). V staged via one gl2lds/wave from pre-transposed vbT.
// ---------------------------------------------------------------------------
#define LDW 72

__global__ __launch_bounds__(512, 4)
void attn_mfma_kernel(const us* __restrict__ q, const float* __restrict__ cache,
                      const us* __restrict__ vbt, us* __restrict__ ctx)
{
    __shared__ __align__(16) us Qs[128 * LDW];   // 18.4 KB; reused as Ps
    __shared__ __align__(16) us Ks[2][64 * LDW]; // 18.4 KB
    __shared__ __align__(16) us Vt[2][64 * 64];  // 16 KB   (total 52.8 KB)

    const int tid  = threadIdx.x;
    const int wave = tid >> 6;          // 0..7
    const int lane = tid & 63;
    const int quad = lane >> 4;
    const int l15  = lane & 15;
    const int xr   = l15 & 7;

    const int bh = blockIdx.x;          // b*32 + h
    const int b  = bh >> 5;
    const int h  = bh & 31;
    const int qt = 7 - blockIdx.y;      // query tile 0..7 (128 rows each)

    const float* kbase = cache + ((size_t)(b * 2 + 0) * T_SEQ) * D_MODEL + h * 64;
    const us* vb_bh = vbt + (size_t)((b * 32 + h) * 64) * 1024;   // [64 d][1024 t]

    // ---- stage Q tile (128q x 64d), bf16 copy ----
    {
        const int qrow = tid >> 2;
        const int qp   = tid & 3;
        const uint4* qg = (const uint4*)(q + (size_t)(b * T_SEQ + qt * 128 + qrow) * D_MODEL
                                           + h * 64 + qp * 16);
        uint4 q0 = qg[0], q1 = qg[1];
        *(uint4*)(Qs + qrow * LDW + qp * 16)     = q0;
        *(uint4*)(Qs + qrow * LDW + qp * 16 + 8) = q1;
    }

    // ---- staging coords ----
    const int ksrow = tid >> 3;                 // 0..63 (K row)
    const int kp8   = tid & 7;                  // 8-d chunk
    const int vrow  = lane >> 3;                // 0..7 (d row within wave's 8)
    const int vchk  = (lane & 7) ^ vrow;        // pre-swizzled key-chunk
    const us* vG = vb_bh + (size_t)(wave * 8 + vrow) * 1024 + vchk * 8;

    const int nkt = 2 * qt + 2;

    // ---- prologue: stage tile 0 into buf 0 ----
    gl2lds16(vG, (us*)Vt[0] + wave * 512);
    {
        const float4* kg = (const float4*)(kbase + (size_t)ksrow * D_MODEL + kp8 * 8);
        float4 k0 = kg[0], k1 = kg[1];
        union { uint4 u; us s[8]; } p;
        p.s[0] = f2b(k0.x); p.s[1] = f2b(k0.y); p.s[2] = f2b(k0.z); p.s[3] = f2b(k0.w);
        p.s[4] = f2b(k1.x); p.s[5] = f2b(k1.y); p.s[6] = f2b(k1.z); p.s[7] = f2b(k1.w);
        *(uint4*)(&Ks[0][ksrow * LDW + kp8 * 8]) = p.u;
    }
    __syncthreads();   // Q + tile-0 staging visible

    // hoist Q A-frags; Qs LDS becomes Ps
    const s16x8 qf0 = *(const s16x8*)(Qs + (wave * 16 + l15) * LDW + quad * 8);
    const s16x8 qf1 = *(const s16x8*)(Qs + (wave * 16 + l15) * LDW + 32 + quad * 8);

    f32x4 oacc[4];
    #pragma unroll
    for (int t = 0; t < 4; ++t) oacc[t] = f32x4{0.f, 0.f, 0.f, 0.f};
    float m_run[4] = {-1e30f, -1e30f, -1e30f, -1e30f};
    float l_run[4] = {0.f, 0.f, 0.f, 0.f};

    for (int kt = 0; kt < nkt; ++kt) {
        const int buf = kt & 1;
        const bool more = (kt + 1 < nkt);

        // ---- T14 issue-early: next tile's V (gl2lds) + K (f32 -> regs) ----
        float4 nk0, nk1;
        if (more) {
            gl2lds16(vG + (kt + 1) * 64, (us*)Vt[buf ^ 1] + wave * 512);
            const float4* kg = (const float4*)(kbase
                + (size_t)((kt + 1) * 64 + ksrow) * D_MODEL + kp8 * 8);
            nk0 = kg[0]; nk1 = kg[1];
        }

        const int kbr = kt * 64 - qt * 128;
        if (kbr < wave * 16 + 16) {          // else fully masked for this wave
            const us* kb_ = Ks[buf];
            const us* vb_ = (const us*)Vt[buf];

            // ---- S = Q @ K^T ----
            f32x4 sacc[4];
            #pragma unroll
            for (int t = 0; t < 4; ++t) sacc[t] = f32x4{0.f, 0.f, 0.f, 0.f};
            #pragma unroll
            for (int t = 0; t < 4; ++t) {
                s16x8 kf0 = *(const s16x8*)(kb_ + (t * 16 + l15) * LDW + quad * 8);
                s16x8 kf1 = *(const s16x8*)(kb_ + (t * 16 + l15) * LDW + 32 + quad * 8);
                sacc[t] = __builtin_amdgcn_mfma_f32_16x16x32_bf16(qf0, kf0, sacc[t], 0, 0, 0);
                sacc[t] = __builtin_amdgcn_mfma_f32_16x16x32_bf16(qf1, kf1, sacc[t], 0, 0, 0);
            }

            if (kbr + 63 > wave * 16) {      // diagonal-straddling: apply mask
                #pragma unroll
                for (int t = 0; t < 4; ++t) {
                    const int keyl = kbr + t * 16 + l15;
                    #pragma unroll
                    for (int r = 0; r < 4; ++r) {
                        if (keyl > wave * 16 + quad * 4 + r) sacc[t][r] = -1e30f;
                    }
                }
            }

            // ---- online softmax (rows live in lane quads) ----
            float rmax[4];
            #pragma unroll
            for (int r = 0; r < 4; ++r)
                rmax[r] = fmaxf(fmaxf(sacc[0][r], sacc[1][r]), fmaxf(sacc[2][r], sacc[3][r]));
            #pragma unroll
            for (int off = 1; off < 16; off <<= 1) {
                #pragma unroll
                for (int r = 0; r < 4; ++r) rmax[r] = fmaxf(rmax[r], __shfl_xor(rmax[r], off, 16));
            }
            float alpha[4];
            #pragma unroll
            for (int r = 0; r < 4; ++r) {
                const float mnew = fmaxf(m_run[r], rmax[r]);
                alpha[r] = __expf(m_run[r] - mnew);
                m_run[r] = mnew;
            }
            float rsum[4] = {0.f, 0.f, 0.f, 0.f};
            #pragma unroll
            for (int t = 0; t < 4; ++t) {
                #pragma unroll
                for (int r = 0; r < 4; ++r) {
                    const float p = __expf(sacc[t][r] - m_run[r]);
                    sacc[t][r] = p;
                    rsum[r] += p;
                }
            }
            #pragma unroll
            for (int off = 1; off < 16; off <<= 1) {
                #pragma unroll
                for (int r = 0; r < 4; ++r) rsum[r] += __shfl_xor(rsum[r], off, 16);
            }
            #pragma unroll
            for (int r = 0; r < 4; ++r) l_run[r] = l_run[r] * alpha[r] + rsum[r];
            #pragma unroll
            for (int t = 0; t < 4; ++t) {
                #pragma unroll
                for (int r = 0; r < 4; ++r) oacc[t][r] *= alpha[r];
            }

            // ---- P -> LDS (per-wave private 16-row slab of reused Qs) ----
            #pragma unroll
            for (int t = 0; t < 4; ++t) {
                #pragma unroll
                for (int r = 0; r < 4; ++r)
                    Qs[(wave * 16 + quad * 4 + r) * LDW + t * 16 + l15] = f2b(sacc[t][r]);
            }
            // same-wave write->read ordered by lgkmcnt

            // ---- O += P @ V^T (V in linear [d][key] LDS, XOR-swizzled) ----
            s16x8 pf0 = *(const s16x8*)(Qs + (wave * 16 + l15) * LDW + quad * 8);
            s16x8 pf1 = *(const s16x8*)(Qs + (wave * 16 + l15) * LDW + 32 + quad * 8);
            #pragma unroll
            for (int t = 0; t < 4; ++t) {
                s16x8 vf0 = *(const s16x8*)(vb_ + (t * 16 + l15) * 64 + ((quad ^ xr) * 8));
                s16x8 vf1 = *(const s16x8*)(vb_ + (t * 16 + l15) * 64 + (((4 + quad) ^ xr) * 8));
                oacc[t] = __builtin_amdgcn_mfma_f32_16x16x32_bf16(pf0, vf0, oacc[t], 0, 0, 0);
                oacc[t] = __builtin_amdgcn_mfma_f32_16x16x32_bf16(pf1, vf1, oacc[t], 0, 0, 0);
            }
        }

        // ---- T14 write-late: K convert + ds_write into buf^1 ----
        if (more) {
            union { uint4 u; us s[8]; } p;
            p.s[0] = f2b(nk0.x); p.s[1] = f2b(nk0.y); p.s[2] = f2b(nk0.z); p.s[3] = f2b(nk0.w);
            p.s[4] = f2b(nk1.x); p.s[5] = f2b(nk1.y); p.s[6] = f2b(nk1.z); p.s[7] = f2b(nk1.w);
            *(uint4*)(&Ks[buf ^ 1][ksrow * LDW + kp8 * 8]) = p.u;
        }
        __syncthreads();   // drains gl2lds (vmcnt) + ds_write (lgkm); flips buffers
    }

    // ---- epilogue: ctx (bf16) = O / l ----
    float invl[4];
    #pragma unroll
    for (int r = 0; r < 4; ++r) invl[r] = 1.0f / l_run[r];
    #pragma unroll
    for (int r = 0; r < 4; ++r) {
        const int qrow = qt * 128 + wave * 16 + quad * 4 + r;
        us* orow = ctx + (size_t)(b * T_SEQ + qrow) * D_MODEL + h * 64;
        #pragma unroll
        for (int t = 0; t < 4; ++t) orow[t * 16 + l15] = f2b(oacc[t][r] * invl[r]);
    }
}

// ---------------------------------------------------------------------------
extern "C" void kernel_launch(void* const* d_in, const int* in_sizes, int n_in,
                              void* d_out, int out_size, void* d_ws, size_t ws_size,
                              hipStream_t stream)
{
    const float* x    = (const float*)d_in[0];
    const int*   idxp = (const int*)d_in[3];
    const float* Wq   = (const float*)d_in[4];
    const float* bq   = (const float*)d_in[5];
    const float* Wk   = (const float*)d_in[6];
    const float* bk   = (const float*)d_in[7];
    const float* Wv   = (const float*)d_in[8];
    const float* bv   = (const float*)d_in[9];
    const float* Wo   = (const float*)d_in[10];
    const float* bo   = (const float*)d_in[11];

    float* out      = (float*)d_out;
    us*    xb       = (us*)d_out;                                   // [0,16MB)
    us*    qb       = (us*)d_out + (size_t)8 * 1024 * 1024;         // [16,32MB)
    float* cacheOut = out + (size_t)4 * T_SEQ * D_MODEL;            // [32,96MB)

    us* WT3  = (us*)d_ws;                                           // [0,24MB)
    us* vbt  = (us*)d_ws;                                           // [0,16MB)  after QKV
    us* ctxb = (us*)d_ws + (size_t)8 * 1024 * 1024;                 // [16,32MB) after QKV
    us* WTo  = (us*)d_ws;                                           // [0,8MB)   after attn

    const dim3 tb(256);

    cvtx_kernel<<<dim3(4096), tb, 0, stream>>>(x, xb);
    wtrans_kernel<<<dim3(32, 32, 3), tb, 0, stream>>>(Wq, Wk, Wv, WT3);

    // fused QKV: N = 6144 -> 48 x 32 = 1536 blocks (R6-proven, 824 TF)
    gemm128_kernel<3><<<dim3(48, 32), tb, 0, stream>>>(
        xb, WT3, bq, bk, bv, (float*)qb, cacheOut, idxp);

    // cache slot1 f32 -> vbT bf16 (coalesced LDS-tiled transpose)
    v2t_kernel<<<dim3(16, 32, 4), tb, 0, stream>>>(cacheOut, vbt);

    attn_mfma_kernel<<<dim3(128, 8), dim3(512), 0, stream>>>(qb, cacheOut, vbt, ctxb);

    wtrans_kernel<<<dim3(32, 32, 1), tb, 0, stream>>>(Wo, Wo, Wo, WTo);

    // O GEMM: N = 2048 -> 16 x 32 = 512 blocks
    gemm128_kernel<0><<<dim3(16, 32), tb, 0, stream>>>(
        ctxb, WTo, bo, nullptr, nullptr, out, nullptr, nullptr);
}